// Round 1
// baseline (5376.504 us; speedup 1.0000x reference)
//
#include <hip/hip_runtime.h>
#include <hip/hip_bf16.h>

#define D 256

typedef __attribute__((ext_vector_type(8))) short short8;
typedef __attribute__((ext_vector_type(8))) unsigned short ushort8;
typedef __attribute__((ext_vector_type(4))) float f32x4;

static __device__ __forceinline__ unsigned short f2bf(float f) {
    union { float f; unsigned u; } u; u.f = f;
    unsigned r = u.u + 0x7FFF + ((u.u >> 16) & 1);   // RNE
    return (unsigned short)(r >> 16);
}

static __device__ __forceinline__ float bf2f(unsigned short b) {
    union { unsigned u; float f; } u; u.u = ((unsigned)b) << 16;
    return u.f;
}

// wT[n][k] = bf16(W[k][n])  -- transpose so B-fragments are k-contiguous
__global__ void cast_w_kernel(const float* __restrict__ W,
                              unsigned short* __restrict__ wT) {
    int n = blockIdx.x;
    int k = threadIdx.x;
    wT[n * D + k] = f2bf(W[k * D + n]);
}

// y[N, 256] (bf16) = x[N, 256] (f32) @ W  via wT (bf16)
// block: 256 threads = 4 waves; block handles 64 rows x 256 cols;
// wave w handles cols [w*64, w*64+64)
__global__ __launch_bounds__(256) void gemm_kernel(
    const float* __restrict__ x, const unsigned short* __restrict__ wT,
    unsigned short* __restrict__ y, int n_nodes) {
    const int lane = threadIdx.x & 63;
    const int wave = threadIdx.x >> 6;
    const int row0 = blockIdx.x * 64;
    const int colb = wave * 64;
    const int koff = (lane >> 4) * 8;   // k-offset within a 32-wide k-tile
    const int rsel = lane & 15;

    for (int mt = 0; mt < 4; ++mt) {
        int row = row0 + mt * 16 + rsel;
        int rowc = row < n_nodes ? row : n_nodes - 1;  // clamp (store is guarded)

        // A fragments for all 8 k-tiles: 8 consecutive f32 -> bf16x8
        short8 a[8];
        const float* xp = x + (size_t)rowc * D + koff;
#pragma unroll
        for (int kt = 0; kt < 8; ++kt) {
            f32x4 lo = *(const f32x4*)(xp + kt * 32);
            f32x4 hi = *(const f32x4*)(xp + kt * 32 + 4);
            short8 af;
            af[0] = (short)f2bf(lo[0]); af[1] = (short)f2bf(lo[1]);
            af[2] = (short)f2bf(lo[2]); af[3] = (short)f2bf(lo[3]);
            af[4] = (short)f2bf(hi[0]); af[5] = (short)f2bf(hi[1]);
            af[6] = (short)f2bf(hi[2]); af[7] = (short)f2bf(hi[3]);
            a[kt] = af;
        }

        f32x4 acc[4];
#pragma unroll
        for (int nt = 0; nt < 4; ++nt) acc[nt] = (f32x4){0.f, 0.f, 0.f, 0.f};

#pragma unroll
        for (int kt = 0; kt < 8; ++kt) {
#pragma unroll
            for (int nt = 0; nt < 4; ++nt) {
                int col = colb + nt * 16 + rsel;
                short8 b = *(const short8*)(wT + (size_t)col * D + kt * 32 + koff);
                acc[nt] = __builtin_amdgcn_mfma_f32_16x16x32_bf16(a[kt], b, acc[nt], 0, 0, 0);
            }
        }

        // C/D layout: col = lane&15, row = (lane>>4)*4 + i
        int crow0 = row0 + mt * 16 + (lane >> 4) * 4;
#pragma unroll
        for (int nt = 0; nt < 4; ++nt) {
            int ccol = colb + nt * 16 + rsel;
#pragma unroll
            for (int i = 0; i < 4; ++i) {
                int r = crow0 + i;
                if (r < n_nodes) y[(size_t)r * D + ccol] = f2bf(acc[nt][i]);
            }
        }
    }
}

// out[dst] += val * y[src]  -- one wave per edge, 4 floats per lane
__global__ __launch_bounds__(256) void scatter_kernel(
    const unsigned short* __restrict__ y,
    const int* __restrict__ esrc, const int* __restrict__ edst,
    const float* __restrict__ eval, float* __restrict__ out, int n_edges) {
    int e = blockIdx.x * 4 + (threadIdx.x >> 6);
    if (e >= n_edges) return;
    int lane = threadIdx.x & 63;
    int s = esrc[e];
    int d = edst[e];
    float v = eval[e];
    const ushort4 raw = *(const ushort4*)(y + (size_t)s * D + lane * 4);
    float* op = out + (size_t)d * D + lane * 4;
    atomicAdd(op + 0, bf2f(raw.x) * v);
    atomicAdd(op + 1, bf2f(raw.y) * v);
    atomicAdd(op + 2, bf2f(raw.z) * v);
    atomicAdd(op + 3, bf2f(raw.w) * v);
}

extern "C" void kernel_launch(void* const* d_in, const int* in_sizes, int n_in,
                              void* d_out, int out_size, void* d_ws, size_t ws_size,
                              hipStream_t stream) {
    const float* x    = (const float*)d_in[0];
    const int*   esrc = (const int*)d_in[1];
    const int*   edst = (const int*)d_in[2];
    const float* eval = (const float*)d_in[3];
    const float* W    = (const float*)d_in[4];
    float* out = (float*)d_out;

    const int n_nodes = in_sizes[0] / D;     // 100000
    const int n_edges = in_sizes[1];         // 1600000

    unsigned short* y  = (unsigned short*)d_ws;            // n_nodes*256 bf16 = 51.2 MB
    unsigned short* wT = y + (size_t)n_nodes * D;          // 256*256 bf16 = 128 KB

    // out must be zeroed every call (harness only poisons once)
    hipMemsetAsync(d_out, 0, (size_t)n_nodes * D * sizeof(float), stream);

    cast_w_kernel<<<D, D, 0, stream>>>(W, wT);

    gemm_kernel<<<(n_nodes + 63) / 64, 256, 0, stream>>>(x, wT, y, n_nodes);

    scatter_kernel<<<(n_edges + 3) / 4, 256, 0, stream>>>(y, esrc, edst, eval, out, n_edges);
}

// Round 2
// 563.883 us; speedup vs baseline: 9.5348x; 9.5348x over previous
//
#include <hip/hip_runtime.h>
#include <hip/hip_bf16.h>

#define D 256

typedef __attribute__((ext_vector_type(8))) short short8;
typedef __attribute__((ext_vector_type(4))) float f32x4;

static __device__ __forceinline__ unsigned short f2bf(float f) {
    union { float f; unsigned u; } u; u.f = f;
    unsigned r = u.u + 0x7FFF + ((u.u >> 16) & 1);   // RNE
    return (unsigned short)(r >> 16);
}

static __device__ __forceinline__ float bf2f(unsigned short b) {
    union { unsigned u; float f; } u; u.u = ((unsigned)b) << 16;
    return u.f;
}

// wT[n][k] = bf16(W[k][n])  -- transpose so B-fragments are k-contiguous
__global__ void cast_w_kernel(const float* __restrict__ W,
                              unsigned short* __restrict__ wT) {
    int n = blockIdx.x;
    int k = threadIdx.x;
    wT[n * D + k] = f2bf(W[k * D + n]);
}

// y[N, 256] (bf16) = x[N, 256] (f32) @ W  via wT (bf16)
__global__ __launch_bounds__(256) void gemm_kernel(
    const float* __restrict__ x, const unsigned short* __restrict__ wT,
    unsigned short* __restrict__ y, int n_nodes) {
    const int lane = threadIdx.x & 63;
    const int wave = threadIdx.x >> 6;
    const int row0 = blockIdx.x * 64;
    const int colb = wave * 64;
    const int koff = (lane >> 4) * 8;
    const int rsel = lane & 15;

    for (int mt = 0; mt < 4; ++mt) {
        int row = row0 + mt * 16 + rsel;
        int rowc = row < n_nodes ? row : n_nodes - 1;

        short8 a[8];
        const float* xp = x + (size_t)rowc * D + koff;
#pragma unroll
        for (int kt = 0; kt < 8; ++kt) {
            f32x4 lo = *(const f32x4*)(xp + kt * 32);
            f32x4 hi = *(const f32x4*)(xp + kt * 32 + 4);
            short8 af;
            af[0] = (short)f2bf(lo[0]); af[1] = (short)f2bf(lo[1]);
            af[2] = (short)f2bf(lo[2]); af[3] = (short)f2bf(lo[3]);
            af[4] = (short)f2bf(hi[0]); af[5] = (short)f2bf(hi[1]);
            af[6] = (short)f2bf(hi[2]); af[7] = (short)f2bf(hi[3]);
            a[kt] = af;
        }

        f32x4 acc[4];
#pragma unroll
        for (int nt = 0; nt < 4; ++nt) acc[nt] = (f32x4){0.f, 0.f, 0.f, 0.f};

#pragma unroll
        for (int kt = 0; kt < 8; ++kt) {
#pragma unroll
            for (int nt = 0; nt < 4; ++nt) {
                int col = colb + nt * 16 + rsel;
                short8 b = *(const short8*)(wT + (size_t)col * D + kt * 32 + koff);
                acc[nt] = __builtin_amdgcn_mfma_f32_16x16x32_bf16(a[kt], b, acc[nt], 0, 0, 0);
            }
        }

        int crow0 = row0 + mt * 16 + (lane >> 4) * 4;
#pragma unroll
        for (int nt = 0; nt < 4; ++nt) {
            int ccol = colb + nt * 16 + rsel;
#pragma unroll
            for (int i = 0; i < 4; ++i) {
                int r = crow0 + i;
                if (r < n_nodes) y[(size_t)r * D + ccol] = f2bf(acc[nt][i]);
            }
        }
    }
}

// deg[dst]++ over all edges (int atomics, HW-coalesced per-wave)
__global__ __launch_bounds__(256) void hist_kernel(
    const int* __restrict__ edst, int* __restrict__ counts, int n_edges) {
    int i = blockIdx.x * blockDim.x + threadIdx.x;
    int stride = gridDim.x * blockDim.x;
    for (; i < n_edges; i += stride) atomicAdd(&counts[edst[i]], 1);
}

// exclusive prefix sum of counts -> offs, single 1024-thread block
__global__ __launch_bounds__(1024) void scan_kernel(
    const int* __restrict__ counts, int* __restrict__ offs, int n) {
    __shared__ int partial[1024];
    int tid = threadIdx.x;
    int chunk = (n + 1023) >> 10;
    int start = tid * chunk;
    int end = start + chunk < n ? start + chunk : n;
    int sum = 0;
    for (int i = start; i < end; ++i) sum += counts[i];
    partial[tid] = sum;
    __syncthreads();
    for (int off = 1; off < 1024; off <<= 1) {
        int v = (tid >= off) ? partial[tid - off] : 0;
        __syncthreads();
        partial[tid] += v;
        __syncthreads();
    }
    int run = partial[tid] - sum;   // exclusive base of this chunk
    for (int i = start; i < end; ++i) { offs[i] = run; run += counts[i]; }
}

// scatter edges into CSR slots; offs[d] ends up = end_d (= start_{d+1})
__global__ __launch_bounds__(256) void fill_kernel(
    const int* __restrict__ esrc, const int* __restrict__ edst,
    const float* __restrict__ eval, int* __restrict__ offs,
    int* __restrict__ csr_src, float* __restrict__ csr_val, int n_edges) {
    int i = blockIdx.x * blockDim.x + threadIdx.x;
    int stride = gridDim.x * blockDim.x;
    for (; i < n_edges; i += stride) {
        int d = edst[i];
        int pos = atomicAdd(&offs[d], 1);
        csr_src[pos] = esrc[i];
        csr_val[pos] = eval[i];
    }
}

// out[d] = sum_{e in CSR[d]} val_e * y[src_e]   -- one wave per dst row
__global__ __launch_bounds__(256) void gather_kernel(
    const unsigned short* __restrict__ y, const int* __restrict__ offs,
    const int* __restrict__ csr_src, const float* __restrict__ csr_val,
    float* __restrict__ out, int n_nodes) {
    int d = blockIdx.x * 4 + (threadIdx.x >> 6);
    if (d >= n_nodes) return;
    int lane = threadIdx.x & 63;
    int beg = d ? offs[d - 1] : 0;   // offs mutated by fill: offs[d] == end_d
    int end = offs[d];

    const unsigned short* yl = y + lane * 4;
    f32x4 acc = (f32x4){0.f, 0.f, 0.f, 0.f};

    int i = beg;
    for (; i + 2 <= end; i += 2) {
        int s0 = csr_src[i];
        int s1 = csr_src[i + 1];
        float v0 = csr_val[i];
        float v1 = csr_val[i + 1];
        ushort4 r0 = *(const ushort4*)(yl + (size_t)s0 * D);
        ushort4 r1 = *(const ushort4*)(yl + (size_t)s1 * D);
        acc[0] += v0 * bf2f(r0.x); acc[1] += v0 * bf2f(r0.y);
        acc[2] += v0 * bf2f(r0.z); acc[3] += v0 * bf2f(r0.w);
        acc[0] += v1 * bf2f(r1.x); acc[1] += v1 * bf2f(r1.y);
        acc[2] += v1 * bf2f(r1.z); acc[3] += v1 * bf2f(r1.w);
    }
    if (i < end) {
        int s0 = csr_src[i];
        float v0 = csr_val[i];
        ushort4 r0 = *(const ushort4*)(yl + (size_t)s0 * D);
        acc[0] += v0 * bf2f(r0.x); acc[1] += v0 * bf2f(r0.y);
        acc[2] += v0 * bf2f(r0.z); acc[3] += v0 * bf2f(r0.w);
    }
    *(f32x4*)(out + (size_t)d * D + lane * 4) = acc;
}

extern "C" void kernel_launch(void* const* d_in, const int* in_sizes, int n_in,
                              void* d_out, int out_size, void* d_ws, size_t ws_size,
                              hipStream_t stream) {
    const float* x    = (const float*)d_in[0];
    const int*   esrc = (const int*)d_in[1];
    const int*   edst = (const int*)d_in[2];
    const float* eval = (const float*)d_in[3];
    const float* W    = (const float*)d_in[4];
    float* out = (float*)d_out;

    const int n_nodes = in_sizes[0] / D;     // 100000
    const int n_edges = in_sizes[1];         // 1600000

    // workspace layout (all 16B-aligned): ~65 MB total
    char* ws = (char*)d_ws;
    unsigned short* y  = (unsigned short*)ws;                 ws += (size_t)n_nodes * D * 2;  // 51.2 MB
    unsigned short* wT = (unsigned short*)ws;                 ws += (size_t)D * D * 2;        // 128 KB
    int*   counts   = (int*)ws;                               ws += (size_t)n_nodes * 4;      // 400 KB
    int*   offs     = (int*)ws;                               ws += (size_t)n_nodes * 4;      // 400 KB
    int*   csr_src  = (int*)ws;                               ws += (size_t)n_edges * 4;      // 6.4 MB
    float* csr_val  = (float*)ws;                             ws += (size_t)n_edges * 4;      // 6.4 MB

    hipMemsetAsync(counts, 0, (size_t)n_nodes * sizeof(int), stream);

    cast_w_kernel<<<D, D, 0, stream>>>(W, wT);
    gemm_kernel<<<(n_nodes + 63) / 64, 256, 0, stream>>>(x, wT, y, n_nodes);

    hist_kernel<<<2048, 256, 0, stream>>>(edst, counts, n_edges);
    scan_kernel<<<1, 1024, 0, stream>>>(counts, offs, n_nodes);
    fill_kernel<<<2048, 256, 0, stream>>>(esrc, edst, eval, offs, csr_src, csr_val, n_edges);

    gather_kernel<<<(n_nodes + 3) / 4, 256, 0, stream>>>(y, offs, csr_src, csr_val, out, n_nodes);
}

// Round 3
// 378.549 us; speedup vs baseline: 14.2029x; 1.4896x over previous
//
#include <hip/hip_runtime.h>
#include <hip/hip_bf16.h>

#define D 256

typedef __attribute__((ext_vector_type(8))) short short8;
typedef __attribute__((ext_vector_type(4))) float f32x4;

static __device__ __forceinline__ unsigned short f2bf(float f) {
    union { float f; unsigned u; } u; u.f = f;
    unsigned r = u.u + 0x7FFF + ((u.u >> 16) & 1);   // RNE
    return (unsigned short)(r >> 16);
}

static __device__ __forceinline__ float bf2f(unsigned short b) {
    union { unsigned u; float f; } u; u.u = ((unsigned)b) << 16;
    return u.f;
}

// wT[n][k] = bf16(W[k][n])  -- transpose so B-fragments are k-contiguous
__global__ void cast_w_kernel(const float* __restrict__ W,
                              unsigned short* __restrict__ wT) {
    int n = blockIdx.x;
    int k = threadIdx.x;
    wT[n * D + k] = f2bf(W[k * D + n]);
}

// y[N, 256] (bf16) = x[N, 256] (f32) @ W  via wT (bf16)
__global__ __launch_bounds__(256) void gemm_kernel(
    const float* __restrict__ x, const unsigned short* __restrict__ wT,
    unsigned short* __restrict__ y, int n_nodes) {
    const int lane = threadIdx.x & 63;
    const int wave = threadIdx.x >> 6;
    const int row0 = blockIdx.x * 64;
    const int colb = wave * 64;
    const int koff = (lane >> 4) * 8;
    const int rsel = lane & 15;

    for (int mt = 0; mt < 4; ++mt) {
        int row = row0 + mt * 16 + rsel;
        int rowc = row < n_nodes ? row : n_nodes - 1;

        short8 a[8];
        const float* xp = x + (size_t)rowc * D + koff;
#pragma unroll
        for (int kt = 0; kt < 8; ++kt) {
            f32x4 lo = *(const f32x4*)(xp + kt * 32);
            f32x4 hi = *(const f32x4*)(xp + kt * 32 + 4);
            short8 af;
            af[0] = (short)f2bf(lo[0]); af[1] = (short)f2bf(lo[1]);
            af[2] = (short)f2bf(lo[2]); af[3] = (short)f2bf(lo[3]);
            af[4] = (short)f2bf(hi[0]); af[5] = (short)f2bf(hi[1]);
            af[6] = (short)f2bf(hi[2]); af[7] = (short)f2bf(hi[3]);
            a[kt] = af;
        }

        f32x4 acc[4];
#pragma unroll
        for (int nt = 0; nt < 4; ++nt) acc[nt] = (f32x4){0.f, 0.f, 0.f, 0.f};

#pragma unroll
        for (int kt = 0; kt < 8; ++kt) {
#pragma unroll
            for (int nt = 0; nt < 4; ++nt) {
                int col = colb + nt * 16 + rsel;
                short8 b = *(const short8*)(wT + (size_t)col * D + kt * 32 + koff);
                acc[nt] = __builtin_amdgcn_mfma_f32_16x16x32_bf16(a[kt], b, acc[nt], 0, 0, 0);
            }
        }

        int crow0 = row0 + mt * 16 + (lane >> 4) * 4;
#pragma unroll
        for (int nt = 0; nt < 4; ++nt) {
            int ccol = colb + nt * 16 + rsel;
#pragma unroll
            for (int i = 0; i < 4; ++i) {
                int r = crow0 + i;
                if (r < n_nodes) y[(size_t)r * D + ccol] = f2bf(acc[nt][i]);
            }
        }
    }
}

// deg[dst]++ over all edges
__global__ __launch_bounds__(256) void hist_kernel(
    const int* __restrict__ edst, int* __restrict__ counts, int n_edges) {
    int i = blockIdx.x * blockDim.x + threadIdx.x;
    int stride = gridDim.x * blockDim.x;
    for (; i < n_edges; i += stride) atomicAdd(&counts[edst[i]], 1);
}

// --- hierarchical exclusive scan (n <= 256*1024 elements) ---
// A: per-block exclusive scan of 1024 counts -> offs (local), blocksum[b] = total
__global__ __launch_bounds__(256) void scan_block_kernel(
    const int* __restrict__ counts, int* __restrict__ offs,
    int* __restrict__ blocksum, int n) {
    __shared__ int tmp[256];
    int tid = threadIdx.x;
    int i0 = blockIdx.x * 1024 + tid * 4;
    int c[4];
    int s = 0;
#pragma unroll
    for (int j = 0; j < 4; ++j) {
        c[j] = (i0 + j < n) ? counts[i0 + j] : 0;
        s += c[j];
    }
    tmp[tid] = s;
    __syncthreads();
    for (int off = 1; off < 256; off <<= 1) {
        int v = (tid >= off) ? tmp[tid - off] : 0;
        __syncthreads();
        tmp[tid] += v;
        __syncthreads();
    }
    int excl = tmp[tid] - s;
    if (tid == 255) blocksum[blockIdx.x] = tmp[255];
    int run = excl;
#pragma unroll
    for (int j = 0; j < 4; ++j) {
        if (i0 + j < n) offs[i0 + j] = run;
        run += c[j];
    }
}

// B: add sum(blocksum[0..b)) to block b's offsets (nb <= 256)
__global__ __launch_bounds__(256) void scan_add_kernel(
    int* __restrict__ offs, const int* __restrict__ blocksum, int n) {
    __shared__ int red[256];
    int tid = threadIdx.x;
    int b = blockIdx.x;
    red[tid] = (tid < b) ? blocksum[tid] : 0;
    __syncthreads();
    for (int off = 128; off > 0; off >>= 1) {
        if (tid < off) red[tid] += red[tid + off];
        __syncthreads();
    }
    int base = red[0];
    if (base == 0) return;   // block 0 (and any all-zero prefix): nothing to add
    int i0 = b * 1024 + tid * 4;
#pragma unroll
    for (int j = 0; j < 4; ++j)
        if (i0 + j < n) offs[i0 + j] += base;
}

// scatter edges into packed CSR slots; offs[d] ends up = end_d
__global__ __launch_bounds__(256) void fill_kernel(
    const int* __restrict__ esrc, const int* __restrict__ edst,
    const float* __restrict__ eval, int* __restrict__ offs,
    int2* __restrict__ csr, int n_edges) {
    int i = blockIdx.x * blockDim.x + threadIdx.x;
    int stride = gridDim.x * blockDim.x;
    for (; i < n_edges; i += stride) {
        int d = edst[i];
        int pos = atomicAdd(&offs[d], 1);
        csr[pos] = make_int2(esrc[i], __float_as_int(eval[i]));
    }
}

// out[d] = sum_{e in CSR[d]} val_e * y[src_e]
// half-wave (32 lanes) per dst row; 16B y-loads, 32B output stores per lane
__global__ __launch_bounds__(256) void gather_kernel(
    const unsigned short* __restrict__ y, const int* __restrict__ offs,
    const int2* __restrict__ csr, float* __restrict__ out, int n_nodes) {
    int d = blockIdx.x * 8 + (threadIdx.x >> 5);
    if (d >= n_nodes) return;
    int lane = threadIdx.x & 31;
    int beg = d ? offs[d - 1] : 0;   // offs[d] == end_d after fill
    int end = offs[d];

    const unsigned short* yl = y + lane * 8;
    float acc[8] = {0.f, 0.f, 0.f, 0.f, 0.f, 0.f, 0.f, 0.f};

    int i = beg;
    for (; i + 2 <= end; i += 2) {
        int2 p0 = csr[i];
        int2 p1 = csr[i + 1];
        float v0 = __int_as_float(p0.y);
        float v1 = __int_as_float(p1.y);
        short8 r0 = *(const short8*)(yl + (size_t)p0.x * D);
        short8 r1 = *(const short8*)(yl + (size_t)p1.x * D);
#pragma unroll
        for (int j = 0; j < 8; ++j) acc[j] += v0 * bf2f((unsigned short)r0[j]);
#pragma unroll
        for (int j = 0; j < 8; ++j) acc[j] += v1 * bf2f((unsigned short)r1[j]);
    }
    if (i < end) {
        int2 p0 = csr[i];
        float v0 = __int_as_float(p0.y);
        short8 r0 = *(const short8*)(yl + (size_t)p0.x * D);
#pragma unroll
        for (int j = 0; j < 8; ++j) acc[j] += v0 * bf2f((unsigned short)r0[j]);
    }

    float* op = out + (size_t)d * D + lane * 8;
    *(f32x4*)(op)     = (f32x4){acc[0], acc[1], acc[2], acc[3]};
    *(f32x4*)(op + 4) = (f32x4){acc[4], acc[5], acc[6], acc[7]};
}

extern "C" void kernel_launch(void* const* d_in, const int* in_sizes, int n_in,
                              void* d_out, int out_size, void* d_ws, size_t ws_size,
                              hipStream_t stream) {
    const float* x    = (const float*)d_in[0];
    const int*   esrc = (const int*)d_in[1];
    const int*   edst = (const int*)d_in[2];
    const float* eval = (const float*)d_in[3];
    const float* W    = (const float*)d_in[4];
    float* out = (float*)d_out;

    const int n_nodes = in_sizes[0] / D;     // 100000
    const int n_edges = in_sizes[1];         // 1600000

    // workspace layout (all 16B-aligned): ~65 MB total
    char* ws = (char*)d_ws;
    unsigned short* y  = (unsigned short*)ws;  ws += (size_t)n_nodes * D * 2;   // 51.2 MB
    unsigned short* wT = (unsigned short*)ws;  ws += (size_t)D * D * 2;         // 128 KB
    int*  counts   = (int*)ws;                 ws += (size_t)n_nodes * 4;       // 400 KB
    int*  offs     = (int*)ws;                 ws += (size_t)n_nodes * 4;       // 400 KB
    int2* csr      = (int2*)ws;                ws += (size_t)n_edges * 8;       // 12.8 MB
    int*  blocksum = (int*)ws;                 ws += 1024;                      // scan partials

    const int nb = (n_nodes + 1023) / 1024;    // 98 (must be <= 256)

    hipMemsetAsync(counts, 0, (size_t)n_nodes * sizeof(int), stream);

    cast_w_kernel<<<D, D, 0, stream>>>(W, wT);
    gemm_kernel<<<(n_nodes + 63) / 64, 256, 0, stream>>>(x, wT, y, n_nodes);

    hist_kernel<<<2048, 256, 0, stream>>>(edst, counts, n_edges);
    scan_block_kernel<<<nb, 256, 0, stream>>>(counts, offs, blocksum, n_nodes);
    scan_add_kernel<<<nb, 256, 0, stream>>>(offs, blocksum, n_nodes);
    fill_kernel<<<2048, 256, 0, stream>>>(esrc, edst, eval, offs, csr, n_edges);

    gather_kernel<<<(n_nodes + 7) / 8, 256, 0, stream>>>(y, offs, csr, out, n_nodes);
}